// Round 1
// baseline (2030.084 us; speedup 1.0000x reference)
//
#include <hip/hip_runtime.h>
#include <hip/hip_bf16.h>
#include <cstdint>
#include <cstddef>

#define NN   100000
#define EE   1600000
#define FIN  512
#define HID  128
#define CC   40
#define KORD 10

// ---------------- degree count ----------------
__global__ __launch_bounds__(256) void k_deg(const int* __restrict__ rowI, int* __restrict__ deg) {
  int i = blockIdx.x * 256 + threadIdx.x;
  if (i < EE) atomicAdd(&deg[rowI[i]], 1);
}

// deg += 1 (self loop), dis = rsqrt(deg)
__global__ __launch_bounds__(256) void k_finalize(int* __restrict__ deg, float* __restrict__ dis) {
  int i = blockIdx.x * 256 + threadIdx.x;
  if (i < NN) {
    int d = deg[i] + 1;
    deg[i] = d;
    dis[i] = rsqrtf((float)d);
  }
}

// ---------------- exclusive scan (3 kernels, 1024 items/block) ----------------
__global__ __launch_bounds__(256) void k_scan1(const int* __restrict__ cnt, int* __restrict__ excl,
                                               int* __restrict__ bsums) {
  __shared__ int s[256];
  int tid = threadIdx.x;
  int base = blockIdx.x * 1024 + tid * 4;
  int v0 = (base + 0 < NN) ? cnt[base + 0] : 0;
  int v1 = (base + 1 < NN) ? cnt[base + 1] : 0;
  int v2 = (base + 2 < NN) ? cnt[base + 2] : 0;
  int v3 = (base + 3 < NN) ? cnt[base + 3] : 0;
  int tsum = v0 + v1 + v2 + v3;
  s[tid] = tsum;
  __syncthreads();
  for (int off = 1; off < 256; off <<= 1) {
    int t = (tid >= off) ? s[tid - off] : 0;
    __syncthreads();
    if (tid >= off) s[tid] += t;
    __syncthreads();
  }
  int run = s[tid] - tsum;
  if (tid == 255) bsums[blockIdx.x] = s[255];
  if (base + 0 < NN) excl[base + 0] = run; run += v0;
  if (base + 1 < NN) excl[base + 1] = run; run += v1;
  if (base + 2 < NN) excl[base + 2] = run; run += v2;
  if (base + 3 < NN) excl[base + 3] = run;
}

__global__ __launch_bounds__(128) void k_scan2(int* __restrict__ bsums, int nb) {
  __shared__ int s[128];
  int tid = threadIdx.x;
  int v = (tid < nb) ? bsums[tid] : 0;
  s[tid] = v;
  __syncthreads();
  for (int off = 1; off < 128; off <<= 1) {
    int t = (tid >= off) ? s[tid - off] : 0;
    __syncthreads();
    if (tid >= off) s[tid] += t;
    __syncthreads();
  }
  if (tid < nb) bsums[tid] = s[tid] - v;
}

__global__ __launch_bounds__(256) void k_scan3(const int* __restrict__ cnt, int* __restrict__ rs,
                                               const int* __restrict__ bsums) {
  int i = blockIdx.x * 256 + threadIdx.x;
  if (i < NN) {
    int v = rs[i] + bsums[i >> 10];
    rs[i] = v;
    if (i == NN - 1) rs[NN] = v + cnt[i];
  }
}

// ---------------- CSR scatter (edges + self loops) ----------------
__global__ __launch_bounds__(256) void k_scatter(const int* __restrict__ rowI, const int* __restrict__ colI,
                                                 const float* __restrict__ dis, const int* __restrict__ rs,
                                                 int* __restrict__ cursor, int* __restrict__ colS,
                                                 float* __restrict__ normS) {
  int i = blockIdx.x * 256 + threadIdx.x;
  if (i >= EE + NN) return;
  int r, c;
  if (i < EE) { r = rowI[i]; c = colI[i]; }
  else        { r = i - EE;  c = r; }
  float w = dis[r] * dis[c];
  int pos = rs[r] + atomicAdd(&cursor[r], 1);
  colS[pos]  = c;
  normS[pos] = w;
}

// ---------------- GEMM1: h1 = relu(x @ W1 + b1), [NN,512]x[512,128] ----------------
__global__ __launch_bounds__(256) void k_gemm1(const float* __restrict__ x, const float* __restrict__ W1,
                                               const float* __restrict__ b1, float* __restrict__ h1) {
  __shared__ float As[16][68];   // padded (+4) to spread store banks
  __shared__ float Bs[16][128];
  int tid = threadIdx.x;
  int blockRow = blockIdx.x * 64;
  int tc = tid & 31;       // col group (x4)
  int tr = tid >> 5;       // row group (x8)
  int aRow = tid >> 2;           // 0..63
  int aCol = (tid & 3) * 4;      // 0,4,8,12
  int bRow = tid >> 4;           // 0..15
  int bCol = (tid & 15) * 8;     // 0..120
  float acc[8][4] = {};
  for (int k0 = 0; k0 < FIN; k0 += 16) {
    int gr = blockRow + aRow;
    float4 av = make_float4(0.f, 0.f, 0.f, 0.f);
    if (gr < NN) av = *(const float4*)&x[(size_t)gr * FIN + k0 + aCol];
    As[aCol + 0][aRow] = av.x;
    As[aCol + 1][aRow] = av.y;
    As[aCol + 2][aRow] = av.z;
    As[aCol + 3][aRow] = av.w;
    float4 bv0 = *(const float4*)&W1[(size_t)(k0 + bRow) * HID + bCol];
    float4 bv1 = *(const float4*)&W1[(size_t)(k0 + bRow) * HID + bCol + 4];
    *(float4*)&Bs[bRow][bCol]     = bv0;
    *(float4*)&Bs[bRow][bCol + 4] = bv1;
    __syncthreads();
#pragma unroll
    for (int kk = 0; kk < 16; ++kk) {
      float a[8], b[4];
#pragma unroll
      for (int i = 0; i < 8; ++i) a[i] = As[kk][tr * 8 + i];
#pragma unroll
      for (int j = 0; j < 4; ++j) b[j] = Bs[kk][tc * 4 + j];
#pragma unroll
      for (int i = 0; i < 8; ++i)
#pragma unroll
        for (int j = 0; j < 4; ++j) acc[i][j] = fmaf(a[i], b[j], acc[i][j]);
    }
    __syncthreads();
  }
#pragma unroll
  for (int i = 0; i < 8; ++i) {
    int r = blockRow + tr * 8 + i;
    if (r < NN) {
#pragma unroll
      for (int j = 0; j < 4; ++j) {
        int c = tc * 4 + j;
        float v = acc[i][j] + b1[c];
        h1[(size_t)r * HID + c] = fmaxf(v, 0.f);
      }
    }
  }
}

// ---------------- GEMM2: t0 = h1 @ W2 + b2 ; out = temp[0]*t0 ----------------
__global__ __launch_bounds__(256) void k_gemm2(const float* __restrict__ h1, const float* __restrict__ W2,
                                               const float* __restrict__ b2, const float* __restrict__ temp,
                                               float* __restrict__ t0, float* __restrict__ outAcc) {
  __shared__ float sW[HID * CC];
  __shared__ float sb[CC];
  int tid = threadIdx.x;
  for (int i = tid; i < HID * CC; i += 256) sW[i] = W2[i];
  if (tid < CC) sb[tid] = b2[tid];
  __syncthreads();
  int gid = blockIdx.x * 256 + tid;   // grid sized exactly NN*CC/256
  int row = gid / CC;
  int col = gid - row * CC;
  const float* hr = h1 + (size_t)row * HID;
  float acc = sb[col];
#pragma unroll 8
  for (int k = 0; k < HID; ++k) acc = fmaf(hr[k], sW[k * CC + col], acc);
  t0[gid] = acc;
  outAcc[gid] = temp[0] * acc;
}

// ---------------- propagation: wave per node ----------------
// MODE 0: vio(t1) = A*vin ;                out += temp[kIdx]*vio
// MODE 1: vio(t_prev) = 2*A*vin - vio ;    out += temp[kIdx]*vio   (in-place)
template <int MODE>
__global__ __launch_bounds__(256) void k_prop(const float* __restrict__ vin, float* __restrict__ vio,
                                              float* __restrict__ outAcc,
                                              const int* __restrict__ colS, const float* __restrict__ normS,
                                              const int* __restrict__ rs, const float* __restrict__ temp,
                                              int kIdx) {
  int node = blockIdx.x * 4 + (threadIdx.x >> 6);
  if (node >= NN) return;
  int f = threadIdx.x & 63;
  int s = rs[node], e = rs[node + 1];
  if (f >= CC) return;
  float acc = 0.f;
  for (int j = s; j < e; ++j) {
    int c = colS[j];
    float w = normS[j];
    acc = fmaf(w, vin[c * CC + f], acc);
  }
  int o = node * CC + f;
  float val;
  if (MODE == 0) val = acc;
  else           val = 2.f * acc - vio[o];
  vio[o] = val;
  outAcc[o] += temp[kIdx] * val;
}

// ---------------- log_softmax rows of 40 ----------------
__global__ __launch_bounds__(256) void k_lsm(float* __restrict__ out) {
  int row = blockIdx.x * 256 + threadIdx.x;
  if (row >= NN) return;
  float* p = out + (size_t)row * CC;
  float v[CC];
#pragma unroll
  for (int i = 0; i < CC / 4; ++i) *(float4*)&v[i * 4] = *(const float4*)&p[i * 4];
  float m = v[0];
#pragma unroll
  for (int i = 1; i < CC; ++i) m = fmaxf(m, v[i]);
  float ssum = 0.f;
#pragma unroll
  for (int i = 0; i < CC; ++i) ssum += expf(v[i] - m);
  float lse = m + logf(ssum);
#pragma unroll
  for (int i = 0; i < CC; ++i) v[i] -= lse;
#pragma unroll
  for (int i = 0; i < CC / 4; ++i) *(float4*)&p[i * 4] = *(float4*)&v[i * 4];
}

extern "C" void kernel_launch(void* const* d_in, const int* in_sizes, int n_in,
                              void* d_out, int out_size, void* d_ws, size_t ws_size,
                              hipStream_t stream) {
  const float* x    = (const float*)d_in[0];
  const int*   ei   = (const int*)d_in[1];
  const float* W1   = (const float*)d_in[2];
  const float* b1   = (const float*)d_in[3];
  const float* W2   = (const float*)d_in[4];
  const float* b2   = (const float*)d_in[5];
  const float* temp = (const float*)d_in[6];
  const int* rowI = ei;
  const int* colI = ei + EE;
  float* out = (float*)d_out;

  char* w = (char*)d_ws;
  auto alloc = [&](size_t bytes) -> void* {
    void* p = (void*)w;
    w += (bytes + 255) & ~(size_t)255;
    return p;
  };
  float* t0    = (float*)alloc((size_t)NN * CC * 4);
  float* t1    = (float*)alloc((size_t)NN * CC * 4);
  int*   deg   = (int*)  alloc((size_t)NN * 4);
  float* dis   = (float*)alloc((size_t)NN * 4);
  int*   rs    = (int*)  alloc((size_t)(NN + 1) * 4);
  int*   cur   = (int*)  alloc((size_t)NN * 4);
  int*   bsums = (int*)  alloc(512 * 4);
  // big region: h1 for GEMMs; reused for CSR arrays after GEMM2 consumed h1
  char* big = (char*)alloc((size_t)NN * HID * 4);
  float* h1    = (float*)big;
  int*   colS  = (int*)big;
  float* normS = (float*)(big + (((size_t)(EE + NN) * 4 + 255) & ~(size_t)255));

  hipMemsetAsync(deg, 0, (size_t)NN * 4, stream);
  hipMemsetAsync(cur, 0, (size_t)NN * 4, stream);

  k_deg<<<(EE + 255) / 256, 256, 0, stream>>>(rowI, deg);
  k_finalize<<<(NN + 255) / 256, 256, 0, stream>>>(deg, dis);

  int nb = (NN + 1023) / 1024;  // 98
  k_scan1<<<nb, 256, 0, stream>>>(deg, rs, bsums);
  k_scan2<<<1, 128, 0, stream>>>(bsums, nb);
  k_scan3<<<(NN + 255) / 256, 256, 0, stream>>>(deg, rs, bsums);

  k_gemm1<<<(NN + 63) / 64, 256, 0, stream>>>(x, W1, b1, h1);
  k_gemm2<<<(NN * CC) / 256, 256, 0, stream>>>(h1, W2, b2, temp, t0, out);

  // h1 is dead now; CSR arrays take over the region
  k_scatter<<<(EE + NN + 255) / 256, 256, 0, stream>>>(rowI, colI, dis, rs, cur, colS, normS);

  // Tx1 = A*Tx0 ; out += temp[1]*Tx1
  k_prop<0><<<NN / 4, 256, 0, stream>>>(t0, t1, out, colS, normS, rs, temp, 1);
  // Chebyshev recurrence, ping-pong
  float* a = t1;  // latest Tx_{k-1}
  float* b = t0;  // Tx_{k-2}, overwritten in place
  for (int k = 2; k <= KORD; ++k) {
    k_prop<1><<<NN / 4, 256, 0, stream>>>(a, b, out, colS, normS, rs, temp, k);
    float* t = a; a = b; b = t;
  }

  k_lsm<<<(NN + 255) / 256, 256, 0, stream>>>(out);
}

// Round 2
// 1187.418 us; speedup vs baseline: 1.7097x; 1.7097x over previous
//
#include <hip/hip_runtime.h>
#include <hip/hip_bf16.h>
#include <cstdint>
#include <cstddef>

#define NN   100000
#define EE   1600000
#define FIN  512
#define HID  128
#define CC   40
#define KORD 10

// ---------------- degree count ----------------
__global__ __launch_bounds__(256) void k_deg(const int* __restrict__ rowI, int* __restrict__ deg) {
  int i = blockIdx.x * 256 + threadIdx.x;
  if (i < EE) atomicAdd(&deg[rowI[i]], 1);
}

// deg += 1 (self loop), dis = rsqrt(deg)
__global__ __launch_bounds__(256) void k_finalize(int* __restrict__ deg, float* __restrict__ dis) {
  int i = blockIdx.x * 256 + threadIdx.x;
  if (i < NN) {
    int d = deg[i] + 1;
    deg[i] = d;
    dis[i] = rsqrtf((float)d);
  }
}

// ---------------- exclusive scan (3 kernels, 1024 items/block) ----------------
__global__ __launch_bounds__(256) void k_scan1(const int* __restrict__ cnt, int* __restrict__ excl,
                                               int* __restrict__ bsums) {
  __shared__ int s[256];
  int tid = threadIdx.x;
  int base = blockIdx.x * 1024 + tid * 4;
  int v0 = (base + 0 < NN) ? cnt[base + 0] : 0;
  int v1 = (base + 1 < NN) ? cnt[base + 1] : 0;
  int v2 = (base + 2 < NN) ? cnt[base + 2] : 0;
  int v3 = (base + 3 < NN) ? cnt[base + 3] : 0;
  int tsum = v0 + v1 + v2 + v3;
  s[tid] = tsum;
  __syncthreads();
  for (int off = 1; off < 256; off <<= 1) {
    int t = (tid >= off) ? s[tid - off] : 0;
    __syncthreads();
    if (tid >= off) s[tid] += t;
    __syncthreads();
  }
  int run = s[tid] - tsum;
  if (tid == 255) bsums[blockIdx.x] = s[255];
  if (base + 0 < NN) excl[base + 0] = run; run += v0;
  if (base + 1 < NN) excl[base + 1] = run; run += v1;
  if (base + 2 < NN) excl[base + 2] = run; run += v2;
  if (base + 3 < NN) excl[base + 3] = run;
}

__global__ __launch_bounds__(128) void k_scan2(int* __restrict__ bsums, int nb) {
  __shared__ int s[128];
  int tid = threadIdx.x;
  int v = (tid < nb) ? bsums[tid] : 0;
  s[tid] = v;
  __syncthreads();
  for (int off = 1; off < 128; off <<= 1) {
    int t = (tid >= off) ? s[tid - off] : 0;
    __syncthreads();
    if (tid >= off) s[tid] += t;
    __syncthreads();
  }
  if (tid < nb) bsums[tid] = s[tid] - v;
}

__global__ __launch_bounds__(256) void k_scan3(const int* __restrict__ cnt, int* __restrict__ rs,
                                               const int* __restrict__ bsums) {
  int i = blockIdx.x * 256 + threadIdx.x;
  if (i < NN) {
    int v = rs[i] + bsums[i >> 10];
    rs[i] = v;
    if (i == NN - 1) rs[NN] = v + cnt[i];
  }
}

// ---------------- CSR scatter (edges + self loops) ----------------
__global__ __launch_bounds__(256) void k_scatter(const int* __restrict__ rowI, const int* __restrict__ colI,
                                                 const float* __restrict__ dis, const int* __restrict__ rs,
                                                 int* __restrict__ cursor, int* __restrict__ colS,
                                                 float* __restrict__ normS) {
  int i = blockIdx.x * 256 + threadIdx.x;
  if (i >= EE + NN) return;
  int r, c;
  if (i < EE) { r = rowI[i]; c = colI[i]; }
  else        { r = i - EE;  c = r; }
  float w = dis[r] * dis[c];
  int pos = rs[r] + atomicAdd(&cursor[r], 1);
  colS[pos]  = c;
  normS[pos] = w;
}

// ---------------- GEMM1: h1 = relu(x @ W1 + b1), [NN,512]x[512,128] ----------------
__global__ __launch_bounds__(256) void k_gemm1(const float* __restrict__ x, const float* __restrict__ W1,
                                               const float* __restrict__ b1, float* __restrict__ h1) {
  __shared__ float As[16][68];   // padded (+4) to spread store banks
  __shared__ float Bs[16][128];
  int tid = threadIdx.x;
  int blockRow = blockIdx.x * 64;
  int tc = tid & 31;       // lane within half-wave: stride-1 col within 32-col group
  int tr = tid >> 5;       // row group (x8)
  int aRow = tid >> 2;           // 0..63
  int aCol = (tid & 3) * 4;      // 0,4,8,12
  int bRow = tid >> 4;           // 0..15
  int bCol = (tid & 15) * 8;     // 0..120
  float acc[8][4] = {};
  for (int k0 = 0; k0 < FIN; k0 += 16) {
    int gr = blockRow + aRow;
    float4 av = make_float4(0.f, 0.f, 0.f, 0.f);
    if (gr < NN) av = *(const float4*)&x[(size_t)gr * FIN + k0 + aCol];
    As[aCol + 0][aRow] = av.x;
    As[aCol + 1][aRow] = av.y;
    As[aCol + 2][aRow] = av.z;
    As[aCol + 3][aRow] = av.w;
    float4 bv0 = *(const float4*)&W1[(size_t)(k0 + bRow) * HID + bCol];
    float4 bv1 = *(const float4*)&W1[(size_t)(k0 + bRow) * HID + bCol + 4];
    *(float4*)&Bs[bRow][bCol]     = bv0;
    *(float4*)&Bs[bRow][bCol + 4] = bv1;
    __syncthreads();
#pragma unroll
    for (int kk = 0; kk < 16; ++kk) {
      float a[8], b[4];
#pragma unroll
      for (int i = 0; i < 8; ++i) a[i] = As[kk][tr * 8 + i];      // broadcast within half-wave
#pragma unroll
      for (int j = 0; j < 4; ++j) b[j] = Bs[kk][j * 32 + tc];     // stride-1 across lanes: conflict-free
#pragma unroll
      for (int i = 0; i < 8; ++i)
#pragma unroll
        for (int j = 0; j < 4; ++j) acc[i][j] = fmaf(a[i], b[j], acc[i][j]);
    }
    __syncthreads();
  }
#pragma unroll
  for (int i = 0; i < 8; ++i) {
    int r = blockRow + tr * 8 + i;
    if (r < NN) {
#pragma unroll
      for (int j = 0; j < 4; ++j) {
        int c = j * 32 + tc;
        float v = acc[i][j] + b1[c];
        h1[(size_t)r * HID + c] = fmaxf(v, 0.f);
      }
    }
  }
}

// ---------------- GEMM2: t0 = h1 @ W2 + b2 ; out = temp[0]*t0 ----------------
__global__ __launch_bounds__(256) void k_gemm2(const float* __restrict__ h1, const float* __restrict__ W2,
                                               const float* __restrict__ b2, const float* __restrict__ temp,
                                               float* __restrict__ t0, float* __restrict__ outAcc) {
  __shared__ float sW[HID * CC];
  __shared__ float sb[CC];
  int tid = threadIdx.x;
  for (int i = tid; i < HID * CC; i += 256) sW[i] = W2[i];
  if (tid < CC) sb[tid] = b2[tid];
  __syncthreads();
  int gid = blockIdx.x * 256 + tid;   // grid sized exactly NN*CC/256
  int row = gid / CC;
  int col = gid - row * CC;
  const float* hr = h1 + (size_t)row * HID;
  float acc = sb[col];
#pragma unroll 8
  for (int k = 0; k < HID; ++k) acc = fmaf(hr[k], sW[k * CC + col], acc);
  t0[gid] = acc;
  outAcc[gid] = temp[0] * acc;
}

// ---------------- propagation: wave per node, edge loop unrolled x4 ----------------
// MODE 0: vio(t1) = A*vin ;                out += temp[kIdx]*vio
// MODE 1: vio(t_prev) = 2*A*vin - vio ;    out += temp[kIdx]*vio   (in-place)
template <int MODE>
__global__ __launch_bounds__(256) void k_prop(const float* __restrict__ vin, float* __restrict__ vio,
                                              float* __restrict__ outAcc,
                                              const int* __restrict__ colS, const float* __restrict__ normS,
                                              const int* __restrict__ rs, const float* __restrict__ temp,
                                              int kIdx) {
  int node = blockIdx.x * 4 + (threadIdx.x >> 6);
  if (node >= NN) return;
  int f = threadIdx.x & 63;
  int s = rs[node], e = rs[node + 1];
  if (f >= CC) return;
  float acc0 = 0.f, acc1 = 0.f, acc2 = 0.f, acc3 = 0.f;
  int j = s;
  // 4 independent gathers in flight per iteration (MLP=4)
  for (; j + 4 <= e; j += 4) {
    int   c0 = colS[j],     c1 = colS[j + 1],  c2 = colS[j + 2],  c3 = colS[j + 3];
    float w0 = normS[j],    w1 = normS[j + 1], w2 = normS[j + 2], w3 = normS[j + 3];
    float v0 = vin[c0 * CC + f];
    float v1 = vin[c1 * CC + f];
    float v2 = vin[c2 * CC + f];
    float v3 = vin[c3 * CC + f];
    acc0 = fmaf(w0, v0, acc0);
    acc1 = fmaf(w1, v1, acc1);
    acc2 = fmaf(w2, v2, acc2);
    acc3 = fmaf(w3, v3, acc3);
  }
  if (j + 2 <= e) {
    int   c0 = colS[j],  c1 = colS[j + 1];
    float w0 = normS[j], w1 = normS[j + 1];
    acc0 = fmaf(w0, vin[c0 * CC + f], acc0);
    acc1 = fmaf(w1, vin[c1 * CC + f], acc1);
    j += 2;
  }
  if (j < e) {
    acc2 = fmaf(normS[j], vin[colS[j] * CC + f], acc2);
  }
  float acc = (acc0 + acc1) + (acc2 + acc3);
  int o = node * CC + f;
  float val;
  if (MODE == 0) val = acc;
  else           val = 2.f * acc - vio[o];
  vio[o] = val;
  outAcc[o] += temp[kIdx] * val;
}

// ---------------- log_softmax rows of 40 ----------------
__global__ __launch_bounds__(256) void k_lsm(float* __restrict__ out) {
  int row = blockIdx.x * 256 + threadIdx.x;
  if (row >= NN) return;
  float* p = out + (size_t)row * CC;
  float v[CC];
#pragma unroll
  for (int i = 0; i < CC / 4; ++i) *(float4*)&v[i * 4] = *(const float4*)&p[i * 4];
  float m = v[0];
#pragma unroll
  for (int i = 1; i < CC; ++i) m = fmaxf(m, v[i]);
  float ssum = 0.f;
#pragma unroll
  for (int i = 0; i < CC; ++i) ssum += expf(v[i] - m);
  float lse = m + logf(ssum);
#pragma unroll
  for (int i = 0; i < CC; ++i) v[i] -= lse;
#pragma unroll
  for (int i = 0; i < CC / 4; ++i) *(float4*)&p[i * 4] = *(float4*)&v[i * 4];
}

extern "C" void kernel_launch(void* const* d_in, const int* in_sizes, int n_in,
                              void* d_out, int out_size, void* d_ws, size_t ws_size,
                              hipStream_t stream) {
  const float* x    = (const float*)d_in[0];
  const int*   ei   = (const int*)d_in[1];
  const float* W1   = (const float*)d_in[2];
  const float* b1   = (const float*)d_in[3];
  const float* W2   = (const float*)d_in[4];
  const float* b2   = (const float*)d_in[5];
  const float* temp = (const float*)d_in[6];
  const int* rowI = ei;
  const int* colI = ei + EE;
  float* out = (float*)d_out;

  char* w = (char*)d_ws;
  auto alloc = [&](size_t bytes) -> void* {
    void* p = (void*)w;
    w += (bytes + 255) & ~(size_t)255;
    return p;
  };
  float* t0    = (float*)alloc((size_t)NN * CC * 4);
  float* t1    = (float*)alloc((size_t)NN * CC * 4);
  int*   deg   = (int*)  alloc((size_t)NN * 4);
  float* dis   = (float*)alloc((size_t)NN * 4);
  int*   rs    = (int*)  alloc((size_t)(NN + 1) * 4);
  int*   cur   = (int*)  alloc((size_t)NN * 4);
  int*   bsums = (int*)  alloc(512 * 4);
  // big region: h1 for GEMMs; reused for CSR arrays after GEMM2 consumed h1
  char* big = (char*)alloc((size_t)NN * HID * 4);
  float* h1    = (float*)big;
  int*   colS  = (int*)big;
  float* normS = (float*)(big + (((size_t)(EE + NN) * 4 + 255) & ~(size_t)255));

  hipMemsetAsync(deg, 0, (size_t)NN * 4, stream);
  hipMemsetAsync(cur, 0, (size_t)NN * 4, stream);

  k_deg<<<(EE + 255) / 256, 256, 0, stream>>>(rowI, deg);
  k_finalize<<<(NN + 255) / 256, 256, 0, stream>>>(deg, dis);

  int nb = (NN + 1023) / 1024;  // 98
  k_scan1<<<nb, 256, 0, stream>>>(deg, rs, bsums);
  k_scan2<<<1, 128, 0, stream>>>(bsums, nb);
  k_scan3<<<(NN + 255) / 256, 256, 0, stream>>>(deg, rs, bsums);

  k_gemm1<<<(NN + 63) / 64, 256, 0, stream>>>(x, W1, b1, h1);
  k_gemm2<<<(NN * CC) / 256, 256, 0, stream>>>(h1, W2, b2, temp, t0, out);

  // h1 is dead now; CSR arrays take over the region
  k_scatter<<<(EE + NN + 255) / 256, 256, 0, stream>>>(rowI, colI, dis, rs, cur, colS, normS);

  // Tx1 = A*Tx0 ; out += temp[1]*Tx1
  k_prop<0><<<NN / 4, 256, 0, stream>>>(t0, t1, out, colS, normS, rs, temp, 1);
  // Chebyshev recurrence, ping-pong
  float* a = t1;  // latest Tx_{k-1}
  float* b = t0;  // Tx_{k-2}, overwritten in place
  for (int k = 2; k <= KORD; ++k) {
    k_prop<1><<<NN / 4, 256, 0, stream>>>(a, b, out, colS, normS, rs, temp, k);
    float* t = a; a = b; b = t;
  }

  k_lsm<<<(NN + 255) / 256, 256, 0, stream>>>(out);
}

// Round 3
// 963.870 us; speedup vs baseline: 2.1062x; 1.2319x over previous
//
#include <hip/hip_runtime.h>
#include <hip/hip_bf16.h>
#include <cstdint>
#include <cstddef>

#define NN   100000
#define EE   1600000
#define FIN  512
#define HID  128
#define CC   40
#define KORD 10

typedef __attribute__((ext_vector_type(4))) float f4;
typedef __attribute__((ext_vector_type(8))) short short8_t;

__device__ __forceinline__ short cvt_bf16(float f) {
  union { float f; unsigned u; } a; a.f = f;
  unsigned r = a.u + 0x7fffu + ((a.u >> 16) & 1u);   // RNE
  return (short)(r >> 16);
}

// ---------------- degree count ----------------
__global__ __launch_bounds__(256) void k_deg(const int* __restrict__ rowI, int* __restrict__ deg) {
  int i = blockIdx.x * 256 + threadIdx.x;
  if (i < EE) atomicAdd(&deg[rowI[i]], 1);
}

__global__ __launch_bounds__(256) void k_finalize(int* __restrict__ deg, float* __restrict__ dis) {
  int i = blockIdx.x * 256 + threadIdx.x;
  if (i < NN) {
    int d = deg[i] + 1;
    deg[i] = d;
    dis[i] = rsqrtf((float)d);
  }
}

// ---------------- exclusive scan ----------------
__global__ __launch_bounds__(256) void k_scan1(const int* __restrict__ cnt, int* __restrict__ excl,
                                               int* __restrict__ bsums) {
  __shared__ int s[256];
  int tid = threadIdx.x;
  int base = blockIdx.x * 1024 + tid * 4;
  int v0 = (base + 0 < NN) ? cnt[base + 0] : 0;
  int v1 = (base + 1 < NN) ? cnt[base + 1] : 0;
  int v2 = (base + 2 < NN) ? cnt[base + 2] : 0;
  int v3 = (base + 3 < NN) ? cnt[base + 3] : 0;
  int tsum = v0 + v1 + v2 + v3;
  s[tid] = tsum;
  __syncthreads();
  for (int off = 1; off < 256; off <<= 1) {
    int t = (tid >= off) ? s[tid - off] : 0;
    __syncthreads();
    if (tid >= off) s[tid] += t;
    __syncthreads();
  }
  int run = s[tid] - tsum;
  if (tid == 255) bsums[blockIdx.x] = s[255];
  if (base + 0 < NN) excl[base + 0] = run; run += v0;
  if (base + 1 < NN) excl[base + 1] = run; run += v1;
  if (base + 2 < NN) excl[base + 2] = run; run += v2;
  if (base + 3 < NN) excl[base + 3] = run;
}

__global__ __launch_bounds__(128) void k_scan2(int* __restrict__ bsums, int nb) {
  __shared__ int s[128];
  int tid = threadIdx.x;
  int v = (tid < nb) ? bsums[tid] : 0;
  s[tid] = v;
  __syncthreads();
  for (int off = 1; off < 128; off <<= 1) {
    int t = (tid >= off) ? s[tid - off] : 0;
    __syncthreads();
    if (tid >= off) s[tid] += t;
    __syncthreads();
  }
  if (tid < nb) bsums[tid] = s[tid] - v;
}

__global__ __launch_bounds__(256) void k_scan3(const int* __restrict__ cnt, int* __restrict__ rs,
                                               const int* __restrict__ bsums) {
  int i = blockIdx.x * 256 + threadIdx.x;
  if (i < NN) {
    int v = rs[i] + bsums[i >> 10];
    rs[i] = v;
    if (i == NN - 1) rs[NN] = v + cnt[i];
  }
}

// ---------------- CSR scatter ----------------
__global__ __launch_bounds__(256) void k_scatter(const int* __restrict__ rowI, const int* __restrict__ colI,
                                                 const float* __restrict__ dis, const int* __restrict__ rs,
                                                 int* __restrict__ cursor, int* __restrict__ colS,
                                                 float* __restrict__ normS) {
  int i = blockIdx.x * 256 + threadIdx.x;
  if (i >= EE + NN) return;
  int r, c;
  if (i < EE) { r = rowI[i]; c = colI[i]; }
  else        { r = i - EE;  c = r; }
  float w = dis[r] * dis[c];
  int pos = rs[r] + atomicAdd(&cursor[r], 1);
  colS[pos]  = c;
  normS[pos] = w;
}

// ---------------- GEMM1 (MFMA bf16): h1 = relu(x @ W1 + b1) ----------------
// 128x128 tile, K-step 32, 4 waves (2x2), per-wave 64x64. Fused f32->bf16 staging.
#define LDK 40   // padded bf16 row stride (32 + 8): b128 lanes spread all 32 banks
__global__ __launch_bounds__(256) void k_gemm1(const float* __restrict__ x, const float* __restrict__ W1,
                                               const float* __restrict__ b1, float* __restrict__ h1) {
  __shared__ __align__(16) short As_s[128][LDK];   // [row][k]
  __shared__ __align__(16) short Bs_s[128][LDK];   // [n][k]  (W1 transposed)
  int tid  = threadIdx.x;
  int wave = tid >> 6, lane = tid & 63;
  int blockRow = blockIdx.x * 128;
  int wr = (wave & 1) * 64, wc = (wave >> 1) * 64;
  int l15 = lane & 15, lk = (lane >> 4) * 8;

  // staging assignments
  int ar = tid >> 1, ak = (tid & 1) * 16;          // A: row, k-offset
  int bn = tid & 127, bk = (tid >> 7) * 16;        // B: n,   k-offset

  f4 acc[4][4] = {};

  for (int k0 = 0; k0 < FIN; k0 += 32) {
    // ---- stage A (x tile, f32 -> bf16) ----
    int gr = blockRow + ar;
    f4 xv0 = {0.f,0.f,0.f,0.f}, xv1 = xv0, xv2 = xv0, xv3 = xv0;
    if (gr < NN) {
      const float* xr = x + (size_t)gr * FIN + k0 + ak;
      xv0 = *(const f4*)&xr[0];
      xv1 = *(const f4*)&xr[4];
      xv2 = *(const f4*)&xr[8];
      xv3 = *(const f4*)&xr[12];
    }
    short8_t p0, p1;
#pragma unroll
    for (int q = 0; q < 4; ++q) {
      p0[q]     = cvt_bf16(xv0[q]);
      p0[q + 4] = cvt_bf16(xv1[q]);
      p1[q]     = cvt_bf16(xv2[q]);
      p1[q + 4] = cvt_bf16(xv3[q]);
    }
    *(short8_t*)&As_s[ar][ak]     = p0;
    *(short8_t*)&As_s[ar][ak + 8] = p1;

    // ---- stage B (W1 tile transposed, f32 -> bf16) ----
    float wv[16];
#pragma unroll
    for (int i = 0; i < 16; ++i) wv[i] = W1[(size_t)(k0 + bk + i) * HID + bn];
    short8_t q0, q1;
#pragma unroll
    for (int i = 0; i < 8; ++i) { q0[i] = cvt_bf16(wv[i]); q1[i] = cvt_bf16(wv[i + 8]); }
    *(short8_t*)&Bs_s[bn][bk]     = q0;
    *(short8_t*)&Bs_s[bn][bk + 8] = q1;

    __syncthreads();

    short8_t afr[4], bfr[4];
#pragma unroll
    for (int m = 0; m < 4; ++m) afr[m] = *(const short8_t*)&As_s[wr + m * 16 + l15][lk];
#pragma unroll
    for (int n = 0; n < 4; ++n) bfr[n] = *(const short8_t*)&Bs_s[wc + n * 16 + l15][lk];
#pragma unroll
    for (int m = 0; m < 4; ++m)
#pragma unroll
      for (int n = 0; n < 4; ++n)
        acc[m][n] = __builtin_amdgcn_mfma_f32_16x16x32_bf16(afr[m], bfr[n], acc[m][n], 0, 0, 0);

    __syncthreads();
  }

  // epilogue: bias + relu. C/D: col = lane&15, row = (lane>>4)*4 + reg
  float bias[4];
#pragma unroll
  for (int n = 0; n < 4; ++n) bias[n] = b1[wc + n * 16 + l15];
#pragma unroll
  for (int m = 0; m < 4; ++m) {
    int baseRow = blockRow + wr + m * 16 + (lane >> 4) * 4;
#pragma unroll
    for (int n = 0; n < 4; ++n) {
      int col = wc + n * 16 + l15;
#pragma unroll
      for (int r = 0; r < 4; ++r) {
        int grow = baseRow + r;
        if (grow < NN) h1[(size_t)grow * HID + col] = fmaxf(acc[m][n][r] + bias[n], 0.f);
      }
    }
  }
}

// ---------------- GEMM2: t0 = h1 @ W2 + b2 ; out = temp[0]*t0 ----------------
__global__ __launch_bounds__(256) void k_gemm2(const float* __restrict__ h1, const float* __restrict__ W2,
                                               const float* __restrict__ b2, const float* __restrict__ temp,
                                               float* __restrict__ t0, float* __restrict__ outAcc) {
  __shared__ float sW[HID * CC];
  __shared__ float sb[CC];
  int tid = threadIdx.x;
  for (int i = tid; i < HID * CC; i += 256) sW[i] = W2[i];
  if (tid < CC) sb[tid] = b2[tid];
  __syncthreads();
  int gid = blockIdx.x * 256 + tid;
  int row = gid / CC;
  int col = gid - row * CC;
  const float* hr = h1 + (size_t)row * HID;
  float acc = sb[col];
#pragma unroll 8
  for (int k = 0; k < HID; ++k) acc = fmaf(hr[k], sW[k * CC + col], acc);
  t0[gid] = acc;
  outAcc[gid] = temp[0] * acc;
}

// ---------------- propagation: 10 lanes/node (float4 features), 6 nodes/wave ----------------
// MODE 0: vio = A*vin ;             out += temp[kIdx]*vio
// MODE 1: vio = 2*A*vin - vio ;     out += temp[kIdx]*vio
template <int MODE>
__global__ __launch_bounds__(256) void k_prop(const float* __restrict__ vin, float* __restrict__ vio,
                                              float* __restrict__ outAcc,
                                              const int* __restrict__ colS, const float* __restrict__ normS,
                                              const int* __restrict__ rs, const float* __restrict__ temp,
                                              int kIdx) {
  int lane = threadIdx.x & 63;
  int wave = threadIdx.x >> 6;
  int sub  = lane / 10;            // 0..6 (6 -> idle)
  int fi   = lane - sub * 10;      // 0..9 -> features fi*4 .. fi*4+3
  int node = blockIdx.x * 24 + wave * 6 + sub;
  bool active = (sub < 6) && (node < NN);
  int s = 0, e = 0;
  if (active) { s = rs[node]; e = rs[node + 1]; }
  f4 a0 = {0.f,0.f,0.f,0.f}, a1 = a0, a2 = a0, a3 = a0;
  int j = s;
  for (; j + 4 <= e; j += 4) {
    int   c0 = colS[j],     c1 = colS[j + 1],  c2 = colS[j + 2],  c3 = colS[j + 3];
    float w0 = normS[j],    w1 = normS[j + 1], w2 = normS[j + 2], w3 = normS[j + 3];
    f4 v0 = *(const f4*)&vin[c0 * CC + fi * 4];
    f4 v1 = *(const f4*)&vin[c1 * CC + fi * 4];
    f4 v2 = *(const f4*)&vin[c2 * CC + fi * 4];
    f4 v3 = *(const f4*)&vin[c3 * CC + fi * 4];
    a0 += w0 * v0; a1 += w1 * v1; a2 += w2 * v2; a3 += w3 * v3;
  }
  for (; j < e; ++j) {
    a0 += normS[j] * *(const f4*)&vin[colS[j] * CC + fi * 4];
  }
  if (active) {
    f4 acc = (a0 + a1) + (a2 + a3);
    size_t o = (size_t)node * CC + fi * 4;
    f4 val;
    if (MODE == 0) val = acc;
    else { f4 prev = *(const f4*)&vio[o]; val = 2.f * acc - prev; }
    *(f4*)&vio[o] = val;
    f4 oa = *(const f4*)&outAcc[o];
    float tk = temp[kIdx];
    *(f4*)&outAcc[o] = oa + tk * val;
  }
}

// ---------------- log_softmax rows of 40 ----------------
__global__ __launch_bounds__(256) void k_lsm(float* __restrict__ out) {
  int row = blockIdx.x * 256 + threadIdx.x;
  if (row >= NN) return;
  float* p = out + (size_t)row * CC;
  float v[CC];
#pragma unroll
  for (int i = 0; i < CC / 4; ++i) *(f4*)&v[i * 4] = *(const f4*)&p[i * 4];
  float m = v[0];
#pragma unroll
  for (int i = 1; i < CC; ++i) m = fmaxf(m, v[i]);
  float ssum = 0.f;
#pragma unroll
  for (int i = 0; i < CC; ++i) ssum += expf(v[i] - m);
  float lse = m + logf(ssum);
#pragma unroll
  for (int i = 0; i < CC; ++i) v[i] -= lse;
#pragma unroll
  for (int i = 0; i < CC / 4; ++i) *(f4*)&p[i * 4] = *(f4*)&v[i * 4];
}

extern "C" void kernel_launch(void* const* d_in, const int* in_sizes, int n_in,
                              void* d_out, int out_size, void* d_ws, size_t ws_size,
                              hipStream_t stream) {
  const float* x    = (const float*)d_in[0];
  const int*   ei   = (const int*)d_in[1];
  const float* W1   = (const float*)d_in[2];
  const float* b1   = (const float*)d_in[3];
  const float* W2   = (const float*)d_in[4];
  const float* b2   = (const float*)d_in[5];
  const float* temp = (const float*)d_in[6];
  const int* rowI = ei;
  const int* colI = ei + EE;
  float* out = (float*)d_out;

  char* w = (char*)d_ws;
  auto alloc = [&](size_t bytes) -> void* {
    void* p = (void*)w;
    w += (bytes + 255) & ~(size_t)255;
    return p;
  };
  float* t0    = (float*)alloc((size_t)NN * CC * 4);
  float* t1    = (float*)alloc((size_t)NN * CC * 4);
  int*   deg   = (int*)  alloc((size_t)NN * 4);
  float* dis   = (float*)alloc((size_t)NN * 4);
  int*   rs    = (int*)  alloc((size_t)(NN + 1) * 4);
  int*   cur   = (int*)  alloc((size_t)NN * 4);
  int*   bsums = (int*)  alloc(512 * 4);
  char* big = (char*)alloc((size_t)NN * HID * 4);
  float* h1    = (float*)big;
  int*   colS  = (int*)big;
  float* normS = (float*)(big + (((size_t)(EE + NN) * 4 + 255) & ~(size_t)255));

  hipMemsetAsync(deg, 0, (size_t)NN * 4, stream);
  hipMemsetAsync(cur, 0, (size_t)NN * 4, stream);

  k_deg<<<(EE + 255) / 256, 256, 0, stream>>>(rowI, deg);
  k_finalize<<<(NN + 255) / 256, 256, 0, stream>>>(deg, dis);

  int nb = (NN + 1023) / 1024;
  k_scan1<<<nb, 256, 0, stream>>>(deg, rs, bsums);
  k_scan2<<<1, 128, 0, stream>>>(bsums, nb);
  k_scan3<<<(NN + 255) / 256, 256, 0, stream>>>(deg, rs, bsums);

  k_gemm1<<<(NN + 127) / 128, 256, 0, stream>>>(x, W1, b1, h1);
  k_gemm2<<<(NN * CC) / 256, 256, 0, stream>>>(h1, W2, b2, temp, t0, out);

  // h1 dead; CSR arrays take over the region
  k_scatter<<<(EE + NN + 255) / 256, 256, 0, stream>>>(rowI, colI, dis, rs, cur, colS, normS);

  k_prop<0><<<(NN + 23) / 24, 256, 0, stream>>>(t0, t1, out, colS, normS, rs, temp, 1);
  float* a = t1;
  float* b = t0;
  for (int k = 2; k <= KORD; ++k) {
    k_prop<1><<<(NN + 23) / 24, 256, 0, stream>>>(a, b, out, colS, normS, rs, temp, k);
    float* t = a; a = b; b = t;
  }

  k_lsm<<<(NN + 255) / 256, 256, 0, stream>>>(out);
}

// Round 4
// 745.482 us; speedup vs baseline: 2.7232x; 1.2929x over previous
//
#include <hip/hip_runtime.h>
#include <hip/hip_bf16.h>
#include <cstdint>
#include <cstddef>

#define NN   100000
#define EE   1600000
#define FIN  512
#define HID  128
#define CC   40
#define KORD 10

typedef __attribute__((ext_vector_type(4))) float f4;
typedef __attribute__((ext_vector_type(8))) short short8_t;
typedef __attribute__((ext_vector_type(2))) unsigned int u2;

__device__ __forceinline__ unsigned short cvt_bf16(float f) {
  union { float f; unsigned u; } a; a.f = f;
  unsigned r = a.u + 0x7fffu + ((a.u >> 16) & 1u);   // RNE
  return (unsigned short)(r >> 16);
}
__device__ __forceinline__ unsigned pk_bf(float a, float b) {
  union { float f; unsigned u; } x, y; x.f = a; y.f = b;
  unsigned ra = x.u + 0x7fffu + ((x.u >> 16) & 1u);
  unsigned rb = y.u + 0x7fffu + ((y.u >> 16) & 1u);
  return (ra >> 16) | (rb & 0xffff0000u);
}
__device__ __forceinline__ f4 cvf(u2 p) {
  union { unsigned u; float f; } a, b, c, d;
  a.u = p.x << 16; b.u = p.x & 0xffff0000u;
  c.u = p.y << 16; d.u = p.y & 0xffff0000u;
  f4 r; r.x = a.f; r.y = b.f; r.z = c.f; r.w = d.f; return r;
}

// ---------------- degree count ----------------
__global__ __launch_bounds__(256) void k_deg(const int* __restrict__ rowI, int* __restrict__ deg) {
  int i = blockIdx.x * 256 + threadIdx.x;
  if (i < EE) atomicAdd(&deg[rowI[i]], 1);
}

// deg += 1 (self loop); dis = 1/sqrt(deg); sqd = sqrt(deg); invd = 1/deg
__global__ __launch_bounds__(256) void k_finalize(int* __restrict__ deg, float* __restrict__ dis,
                                                  float* __restrict__ sqd, float* __restrict__ invd) {
  int i = blockIdx.x * 256 + threadIdx.x;
  if (i < NN) {
    int d = deg[i] + 1;
    deg[i] = d;
    float fd = (float)d;
    dis[i]  = rsqrtf(fd);
    sqd[i]  = sqrtf(fd);
    invd[i] = 1.0f / fd;
  }
}

// ---------------- exclusive scan ----------------
__global__ __launch_bounds__(256) void k_scan1(const int* __restrict__ cnt, int* __restrict__ excl,
                                               int* __restrict__ bsums) {
  __shared__ int s[256];
  int tid = threadIdx.x;
  int base = blockIdx.x * 1024 + tid * 4;
  int v0 = (base + 0 < NN) ? cnt[base + 0] : 0;
  int v1 = (base + 1 < NN) ? cnt[base + 1] : 0;
  int v2 = (base + 2 < NN) ? cnt[base + 2] : 0;
  int v3 = (base + 3 < NN) ? cnt[base + 3] : 0;
  int tsum = v0 + v1 + v2 + v3;
  s[tid] = tsum;
  __syncthreads();
  for (int off = 1; off < 256; off <<= 1) {
    int t = (tid >= off) ? s[tid - off] : 0;
    __syncthreads();
    if (tid >= off) s[tid] += t;
    __syncthreads();
  }
  int run = s[tid] - tsum;
  if (tid == 255) bsums[blockIdx.x] = s[255];
  if (base + 0 < NN) excl[base + 0] = run; run += v0;
  if (base + 1 < NN) excl[base + 1] = run; run += v1;
  if (base + 2 < NN) excl[base + 2] = run; run += v2;
  if (base + 3 < NN) excl[base + 3] = run;
}

__global__ __launch_bounds__(128) void k_scan2(int* __restrict__ bsums, int nb) {
  __shared__ int s[128];
  int tid = threadIdx.x;
  int v = (tid < nb) ? bsums[tid] : 0;
  s[tid] = v;
  __syncthreads();
  for (int off = 1; off < 128; off <<= 1) {
    int t = (tid >= off) ? s[tid - off] : 0;
    __syncthreads();
    if (tid >= off) s[tid] += t;
    __syncthreads();
  }
  if (tid < nb) bsums[tid] = s[tid] - v;
}

// writes rs and cur (cur = running cursor initialized to row start)
__global__ __launch_bounds__(256) void k_scan3(const int* __restrict__ cnt, int* __restrict__ rs,
                                               int* __restrict__ cur, const int* __restrict__ bsums) {
  int i = blockIdx.x * 256 + threadIdx.x;
  if (i < NN) {
    int v = rs[i] + bsums[i >> 10];
    rs[i] = v;
    cur[i] = v;
    if (i == NN - 1) rs[NN] = v + cnt[i];
  }
}

// ---------------- CSR scatter: colS holds BYTE offsets (c*80) ----------------
__global__ __launch_bounds__(256) void k_scatter(const int* __restrict__ rowI, const int* __restrict__ colI,
                                                 int* __restrict__ cur, int* __restrict__ colS) {
  int i = blockIdx.x * 256 + threadIdx.x;
  if (i >= EE + NN) return;
  int r, c;
  if (i < EE) { r = rowI[i]; c = colI[i]; }
  else        { r = i - EE;  c = r; }
  int pos = atomicAdd(&cur[r], 1);
  colS[pos] = c * 80;           // byte offset into bf16 shadow [node][40]
}

// ---------------- W1 -> bf16, k-tiled transposed layout ----------------
// W1Tt[t][n][kk] at t*4096 + n*32 + kk, t = k/32, kk = k%32
__global__ __launch_bounds__(256) void k_w1t(const float* __restrict__ W1, unsigned short* __restrict__ W1T) {
  int idx = blockIdx.x * 256 + threadIdx.x;   // 0..65535
  int k = idx >> 7;
  int n = idx & 127;
  float v = W1[idx];                           // W1[k][n]
  W1T[(k >> 5) * 4096 + n * 32 + (k & 31)] = cvt_bf16(v);
}

// ---------------- GEMM1 (MFMA bf16): h1 = relu(x @ W1 + b1) ----------------
#define LDK 40
__global__ __launch_bounds__(256) void k_gemm1(const float* __restrict__ x, const unsigned short* __restrict__ W1T,
                                               const float* __restrict__ b1, float* __restrict__ h1) {
  __shared__ __align__(16) short As_s[128][LDK];
  __shared__ __align__(16) short Bs_s[128][LDK];
  int tid  = threadIdx.x;
  int wave = tid >> 6, lane = tid & 63;
  int blockRow = blockIdx.x * 128;
  int wr = (wave & 1) * 64, wc = (wave >> 1) * 64;
  int l15 = lane & 15, lk = (lane >> 4) * 8;

  int ar = tid >> 1, ak = (tid & 1) * 16;          // A staging

  f4 acc[4][4] = {};

  for (int k0 = 0; k0 < FIN; k0 += 32) {
    // ---- stage A (x tile, f32 -> bf16) ----
    int gr = blockRow + ar;
    f4 xv0 = {0.f,0.f,0.f,0.f}, xv1 = xv0, xv2 = xv0, xv3 = xv0;
    if (gr < NN) {
      const float* xr = x + (size_t)gr * FIN + k0 + ak;
      xv0 = *(const f4*)&xr[0];
      xv1 = *(const f4*)&xr[4];
      xv2 = *(const f4*)&xr[8];
      xv3 = *(const f4*)&xr[12];
    }
    short8_t p0, p1;
#pragma unroll
    for (int q = 0; q < 4; ++q) {
      p0[q]     = (short)cvt_bf16(xv0[q]);
      p0[q + 4] = (short)cvt_bf16(xv1[q]);
      p1[q]     = (short)cvt_bf16(xv2[q]);
      p1[q + 4] = (short)cvt_bf16(xv3[q]);
    }
    *(short8_t*)&As_s[ar][ak]     = p0;
    *(short8_t*)&As_s[ar][ak + 8] = p1;

    // ---- stage B: coalesced pre-converted tile (8 KB) ----
    const unsigned short* Wt = W1T + (k0 >> 5) * 4096;
    short8_t q0 = *(const short8_t*)&Wt[tid * 16];
    short8_t q1 = *(const short8_t*)&Wt[tid * 16 + 8];
    int bn = tid >> 1, bkk = (tid & 1) * 16;
    *(short8_t*)&Bs_s[bn][bkk]     = q0;
    *(short8_t*)&Bs_s[bn][bkk + 8] = q1;

    __syncthreads();

    short8_t afr[4], bfr[4];
#pragma unroll
    for (int m = 0; m < 4; ++m) afr[m] = *(const short8_t*)&As_s[wr + m * 16 + l15][lk];
#pragma unroll
    for (int n = 0; n < 4; ++n) bfr[n] = *(const short8_t*)&Bs_s[wc + n * 16 + l15][lk];
#pragma unroll
    for (int m = 0; m < 4; ++m)
#pragma unroll
      for (int n = 0; n < 4; ++n)
        acc[m][n] = __builtin_amdgcn_mfma_f32_16x16x32_bf16(afr[m], bfr[n], acc[m][n], 0, 0, 0);

    __syncthreads();
  }

  float bias[4];
#pragma unroll
  for (int n = 0; n < 4; ++n) bias[n] = b1[wc + n * 16 + l15];
#pragma unroll
  for (int m = 0; m < 4; ++m) {
    int baseRow = blockRow + wr + m * 16 + (lane >> 4) * 4;
#pragma unroll
    for (int n = 0; n < 4; ++n) {
      int col = wc + n * 16 + l15;
#pragma unroll
      for (int r = 0; r < 4; ++r) {
        int grow = baseRow + r;
        if (grow < NN) h1[(size_t)grow * HID + col] = fmaxf(acc[m][n][r] + bias[n], 0.f);
      }
    }
  }
}

// ---------------- GEMM2: out = temp0*Tx0 ; w0 = Tx0 * dis ----------------
__global__ __launch_bounds__(256) void k_gemm2(const float* __restrict__ h1, const float* __restrict__ W2,
                                               const float* __restrict__ b2, const float* __restrict__ temp,
                                               const float* __restrict__ dis,
                                               float* __restrict__ w0, float* __restrict__ outAcc) {
  __shared__ float sW[HID * CC];
  __shared__ float sb[CC];
  int tid = threadIdx.x;
  for (int i = tid; i < HID * CC; i += 256) sW[i] = W2[i];
  if (tid < CC) sb[tid] = b2[tid];
  __syncthreads();
  int gid = blockIdx.x * 256 + tid;
  int row = gid / CC;
  int col = gid - row * CC;
  const float* hr = h1 + (size_t)row * HID;
  float acc = sb[col];
#pragma unroll 8
  for (int k = 0; k < HID; ++k) acc = fmaf(hr[k], sW[k * CC + col], acc);
  outAcc[gid] = temp[0] * acc;
  w0[gid] = acc * dis[row];
}

// ---------------- f32 -> bf16 shadow convert (4 floats / thread) ----------------
__global__ __launch_bounds__(256) void k_cvt(const float* __restrict__ v, unsigned short* __restrict__ sh) {
  int i = blockIdx.x * 256 + threadIdx.x;
  if (i * 4 >= NN * CC) return;
  f4 t = *(const f4*)&v[i * 4];
  u2 p; p.x = pk_bf(t.x, t.y); p.y = pk_bf(t.z, t.w);
  *(u2*)&sh[i * 4] = p;
}

// ---------------- propagation: 10 lanes/node, 6 nodes/wave, bf16 shadow gather ----------------
// MODE 0: w1 = invd*Sum(sh w0) ;              vio = w1
// MODE 1: wk = 2*invd*Sum(sh w_{k-1}) - vio ; vio = wk   (vio f32 RMW)
// both:   shOut = bf16(wk) ; out += temp[kIdx]*sqd*wk
template <int MODE>
__global__ __launch_bounds__(256) void k_prop(const unsigned short* __restrict__ shIn,
                                              unsigned short* __restrict__ shOut,
                                              float* __restrict__ vio,
                                              float* __restrict__ outAcc,
                                              const int* __restrict__ colS,
                                              const int* __restrict__ rs,
                                              const float* __restrict__ invd, const float* __restrict__ sqd,
                                              const float* __restrict__ temp, int kIdx) {
  int lane = threadIdx.x & 63;
  int wave = threadIdx.x >> 6;
  int sub  = lane / 10;
  int fi   = lane - sub * 10;
  int node = blockIdx.x * 24 + wave * 6 + sub;
  bool active = (sub < 6) && (node < NN);
  int s = 0, e = 0;
  if (active) { s = rs[node]; e = rs[node + 1]; }
  const char* base = (const char*)shIn + fi * 8;
  f4 a0 = {0.f,0.f,0.f,0.f}, a1 = a0, a2 = a0, a3 = a0;
  int j = s;
  for (; j + 8 <= e; j += 8) {
    int c0 = colS[j],     c1 = colS[j + 1], c2 = colS[j + 2], c3 = colS[j + 3];
    int c4 = colS[j + 4], c5 = colS[j + 5], c6 = colS[j + 6], c7 = colS[j + 7];
    u2 p0 = *(const u2*)(base + c0);
    u2 p1 = *(const u2*)(base + c1);
    u2 p2 = *(const u2*)(base + c2);
    u2 p3 = *(const u2*)(base + c3);
    u2 p4 = *(const u2*)(base + c4);
    u2 p5 = *(const u2*)(base + c5);
    u2 p6 = *(const u2*)(base + c6);
    u2 p7 = *(const u2*)(base + c7);
    a0 += cvf(p0); a1 += cvf(p1); a2 += cvf(p2); a3 += cvf(p3);
    a0 += cvf(p4); a1 += cvf(p5); a2 += cvf(p6); a3 += cvf(p7);
  }
  if (j + 4 <= e) {
    int c0 = colS[j], c1 = colS[j + 1], c2 = colS[j + 2], c3 = colS[j + 3];
    u2 p0 = *(const u2*)(base + c0);
    u2 p1 = *(const u2*)(base + c1);
    u2 p2 = *(const u2*)(base + c2);
    u2 p3 = *(const u2*)(base + c3);
    a0 += cvf(p0); a1 += cvf(p1); a2 += cvf(p2); a3 += cvf(p3);
    j += 4;
  }
  if (j + 2 <= e) {
    u2 p0 = *(const u2*)(base + colS[j]);
    u2 p1 = *(const u2*)(base + colS[j + 1]);
    a0 += cvf(p0); a1 += cvf(p1);
    j += 2;
  }
  if (j < e) a2 += cvf(*(const u2*)(base + colS[j]));

  if (active) {
    f4 sum = (a0 + a1) + (a2 + a3);
    float iv = invd[node], sq = sqd[node], tk = temp[kIdx];
    size_t o = (size_t)node * CC + fi * 4;
    f4 w;
    if (MODE == 0) w = iv * sum;
    else { f4 prev = *(const f4*)&vio[o]; w = (2.f * iv) * sum - prev; }
    *(f4*)&vio[o] = w;
    u2 p; p.x = pk_bf(w.x, w.y); p.y = pk_bf(w.z, w.w);
    *(u2*)((char*)shOut + (size_t)node * 80 + fi * 8) = p;
    f4 oa = *(const f4*)&outAcc[o];
    *(f4*)&outAcc[o] = oa + (tk * sq) * w;
  }
}

// ---------------- log_softmax rows of 40 ----------------
__global__ __launch_bounds__(256) void k_lsm(float* __restrict__ out) {
  int row = blockIdx.x * 256 + threadIdx.x;
  if (row >= NN) return;
  float* p = out + (size_t)row * CC;
  float v[CC];
#pragma unroll
  for (int i = 0; i < CC / 4; ++i) *(f4*)&v[i * 4] = *(const f4*)&p[i * 4];
  float m = v[0];
#pragma unroll
  for (int i = 1; i < CC; ++i) m = fmaxf(m, v[i]);
  float ssum = 0.f;
#pragma unroll
  for (int i = 0; i < CC; ++i) ssum += expf(v[i] - m);
  float lse = m + logf(ssum);
#pragma unroll
  for (int i = 0; i < CC; ++i) v[i] -= lse;
#pragma unroll
  for (int i = 0; i < CC / 4; ++i) *(f4*)&p[i * 4] = *(f4*)&v[i * 4];
}

extern "C" void kernel_launch(void* const* d_in, const int* in_sizes, int n_in,
                              void* d_out, int out_size, void* d_ws, size_t ws_size,
                              hipStream_t stream) {
  const float* x    = (const float*)d_in[0];
  const int*   ei   = (const int*)d_in[1];
  const float* W1   = (const float*)d_in[2];
  const float* b1   = (const float*)d_in[3];
  const float* W2   = (const float*)d_in[4];
  const float* b2   = (const float*)d_in[5];
  const float* temp = (const float*)d_in[6];
  const int* rowI = ei;
  const int* colI = ei + EE;
  float* out = (float*)d_out;

  char* w = (char*)d_ws;
  auto alloc = [&](size_t bytes) -> void* {
    void* p = (void*)w;
    w += (bytes + 255) & ~(size_t)255;
    return p;
  };
  float* t0    = (float*)alloc((size_t)NN * CC * 4);
  float* t1    = (float*)alloc((size_t)NN * CC * 4);
  int*   deg   = (int*)  alloc((size_t)NN * 4);
  float* dis   = (float*)alloc((size_t)NN * 4);
  float* sqd   = (float*)alloc((size_t)NN * 4);
  float* invd  = (float*)alloc((size_t)NN * 4);
  int*   rs    = (int*)  alloc((size_t)(NN + 1) * 4);
  int*   cur   = (int*)  alloc((size_t)NN * 4);
  int*   bsums = (int*)  alloc(512 * 4);
  unsigned short* W1T = (unsigned short*)alloc((size_t)FIN * HID * 2);
  char* big = (char*)alloc((size_t)NN * HID * 4);
  // big region: h1 (51.2MB) during GEMMs; afterwards: colS [0,6.8M), sh0 @+8M, sh1 @+16M
  float* h1 = (float*)big;
  int*   colS = (int*)big;
  unsigned short* sh0 = (unsigned short*)(big + ((size_t)8 << 20));
  unsigned short* sh1 = (unsigned short*)(big + ((size_t)16 << 20));

  hipMemsetAsync(deg, 0, (size_t)NN * 4, stream);

  k_deg<<<(EE + 255) / 256, 256, 0, stream>>>(rowI, deg);
  k_finalize<<<(NN + 255) / 256, 256, 0, stream>>>(deg, dis, sqd, invd);

  int nb = (NN + 1023) / 1024;
  k_scan1<<<nb, 256, 0, stream>>>(deg, rs, bsums);
  k_scan2<<<1, 128, 0, stream>>>(bsums, nb);
  k_scan3<<<(NN + 255) / 256, 256, 0, stream>>>(deg, rs, cur, bsums);

  k_w1t<<<FIN * HID / 256, 256, 0, stream>>>(W1, W1T);
  k_gemm1<<<(NN + 127) / 128, 256, 0, stream>>>(x, W1T, b1, h1);
  k_gemm2<<<(NN * CC) / 256, 256, 0, stream>>>(h1, W2, b2, temp, dis, t0, out);

  // h1 dead: CSR + shadows take over the big region
  k_scatter<<<(EE + NN + 255) / 256, 256, 0, stream>>>(rowI, colI, cur, colS);
  k_cvt<<<(NN * CC / 4 + 255) / 256, 256, 0, stream>>>(t0, sh0);

  int G = (NN + 23) / 24;
  unsigned short* sh[2] = {sh0, sh1};
  float* tb[2] = {t0, t1};
  // k=1: w1 = invd * A w0
  k_prop<0><<<G, 256, 0, stream>>>(sh[0], sh[1], t1, out, colS, rs, invd, sqd, temp, 1);
  // k=2..10: wk = 2*invd*A w_{k-1} - w_{k-2}
  for (int k = 2; k <= KORD; ++k) {
    k_prop<1><<<G, 256, 0, stream>>>(sh[(k - 1) & 1], sh[k & 1], tb[k & 1], out, colS, rs, invd, sqd, temp, k);
  }

  k_lsm<<<(NN + 255) / 256, 256, 0, stream>>>(out);
}